// Round 12
// baseline (493.872 us; speedup 1.0000x reference)
//
#include <hip/hip_runtime.h>
#include <hip/hip_bf16.h>

#define B_DIM 256
#define NTOK (256 * 512)
#define W1_LD 517
#define TPB 64  // tokens per k_token block

// workspace float offsets
#define WS_DIT 0
#define WS_E 256             // holds 2*e
#define WS_C0 512
#define WS_W1F 1024          // fp8 frag-ordered [8 nblk][16 ks][64 lane][8B]
#define WS_W1X 17408         // bf16 extras step [8 nblk][64 lane][8]
#define WS_SCORE 20480       // [NTOK]
#define WS_CNT 151552        // int cnt[256], zeroed by k_setup each call

typedef __attribute__((ext_vector_type(8))) short bf16x8;
typedef __attribute__((ext_vector_type(4))) float f32x4;
typedef long long i64;

__device__ __forceinline__ unsigned pk2(float a, float b) {
  __hip_bfloat162 h = __float22bfloat162_rn(make_float2(a, b));
  unsigned r;
  __builtin_memcpy(&r, &h, 4);
  return r;
}
__device__ __forceinline__ unsigned pk4f8(float a, float b, float c, float d) {
  int r = __builtin_amdgcn_cvt_pk_fp8_f32(a, b, 0, false);
  r = __builtin_amdgcn_cvt_pk_fp8_f32(c, d, r, true);
  return (unsigned)r;
}

// DPP cross-lane add (VALU pipe)
template <int CTRL>
__device__ __forceinline__ float dpp_add(float v) {
  int s = __builtin_amdgcn_update_dpp(0, __float_as_int(v), CTRL, 0xf, 0xf,
                                      true);
  return v + __int_as_float(s);
}
__device__ __forceinline__ float row8_sum(float v) {
  v = dpp_add<0xB1>(v);   // quad_perm xor1
  v = dpp_add<0x4E>(v);   // quad_perm xor2
  v = dpp_add<0x141>(v);  // row_half_mirror
  return v;
}
__device__ __forceinline__ float row16_sum(float v) {
  v = dpp_add<0xB1>(v);
  v = dpp_add<0x4E>(v);
  v = dpp_add<0x124>(v);  // row_ror:4
  v = dpp_add<0x128>(v);  // row_ror:8
  return v;
}

__device__ __forceinline__ float wave_sum(float v) {
#pragma unroll
  for (int off = 32; off > 0; off >>= 1) v += __shfl_xor(v, off, 64);
  return v;
}
__device__ __forceinline__ float wave_max(float v) {
#pragma unroll
  for (int off = 32; off > 0; off >>= 1) v = fmaxf(v, __shfl_xor(v, off, 64));
  return v;
}
__device__ __forceinline__ float block_sum(float v, float* scr) {
  v = wave_sum(v);
  int wid = threadIdx.x >> 6;
  __syncthreads();
  if ((threadIdx.x & 63) == 0) scr[wid] = v;
  __syncthreads();
  return scr[0] + scr[1] + scr[2] + scr[3];
}

// ---------------------------------------------------------------------------
// K-axis reorder: position p in [0,512) -> W1 column
//   (p&15)<8 ? (p>>4)*8 + (p&7) : 256 + (p>>4)*8 + (p&7)
// ---------------------------------------------------------------------------
__global__ __launch_bounds__(256) void k_setup(
    const float* __restrict__ W1, const float* __restrict__ b1,
    const float* __restrict__ mu_c, const float* __restrict__ log_tau2,
    const float* __restrict__ log_prior, float* __restrict__ wsc) {
  const int tid = threadIdx.x;
  const int h = blockIdx.x;
  const float* wr = W1 + h * W1_LD;
  {
    const int p = 2 * tid;
    const int c0 = ((p & 15) < 8) ? (p >> 4) * 8 + (p & 7)
                                  : 256 + (p >> 4) * 8 + (p & 7);
    const int p1 = p + 1;
    const int c1 = ((p1 & 15) < 8) ? (p1 >> 4) * 8 + (p1 & 7)
                                   : 256 + (p1 >> 4) * 8 + (p1 & 7);
    const int pk = __builtin_amdgcn_cvt_pk_fp8_f32(wr[c0], wr[c1], 0, false);
    char* w1f = (char*)(wsc + WS_W1F);
    const int off = (h >> 4) * 8192 + (p >> 5) * 512 +
                    (((p >> 3) & 3) * 16 + (h & 15)) * 8 + (p & 7);
    *(ushort*)(w1f + off) = (ushort)pk;
  }
  if (tid == 0) {
    ushort* w1x = (ushort*)(wsc + WS_W1X);
    const int nb = (h >> 4) * 512;
    uint4 g0;
    g0.x = pk2(wr[512], wr[513]);
    g0.y = pk2(wr[514], wr[515]);
    g0.z = pk2(wr[516], b1[h]);
    g0.w = 0u;
    *(uint4*)(w1x + nb + (h & 15) * 8) = g0;
    const uint4 z = {0u, 0u, 0u, 0u};
    *(uint4*)(w1x + nb + (16 + (h & 15)) * 8) = z;
    *(uint4*)(w1x + nb + (32 + (h & 15)) * 8) = z;
    *(uint4*)(w1x + nb + (48 + (h & 15)) * 8) = z;
  }
  // zero the per-row completion counters (handles 0xAA poison + replays)
  if (blockIdx.x == 1) {
    ((int*)(wsc + WS_CNT))[tid] = 0;
  }

  if (blockIdx.x == 0) {
    __shared__ float scr[4];
    float lt0 = log_tau2[tid], lt1 = log_tau2[256 + tid];
    float mc0 = mu_c[tid], mc1 = mu_c[256 + tid];
    float it0 = __expf(-lt0), it1 = __expf(-lt1);
    wsc[WS_DIT + tid] = it1 - it0;
    wsc[WS_E + tid] = 2.0f * (mc1 * it1 - mc0 * it0);
    float g = mc1 * mc1 * it1 - mc0 * mc0 * it0 + (lt1 - lt0);
    float sg = block_sum(g, scr);
    if (tid == 0) wsc[WS_C0] = (log_prior[1] - log_prior[0]) - 0.5f * sg;
  }
}

// ---------------------------------------------------------------------------
// Fused token + row kernel: 64 tokens/block, 512 threads (8 waves),
// 4 blocks/CU. Phase 1/2 identical to R11. Then each block signals its row
// (8 blocks/row) via device-scope fence+atomic; the LAST block of a row
// runs the row reduction (softmax-mix, time decay, noisy-OR) with 512
// threads (1 token each). No spin: only the last arriver works.
// ---------------------------------------------------------------------------
__global__ __launch_bounds__(512, 8) void k_fused(
    const float* __restrict__ mu, const float* __restrict__ logvar,
    const float* __restrict__ minutes, const float* __restrict__ W2g,
    const float* __restrict__ b2, const float* __restrict__ wsc,
    const float* __restrict__ alpha_logits,
    const float* __restrict__ attn_lambda_logit,
    const float* __restrict__ decay_rate_log, float* __restrict__ out_total,
    float* __restrict__ out_s, float* __restrict__ ws_score,
    float* __restrict__ a_io, int* __restrict__ cnt) {
  __shared__ __align__(16) char A_l[TPB * 512];   // 32KB fp8, XOR-swizzled
  __shared__ __align__(16) ushort axl[TPB * 32];  // 4KB bf16 extras rows
  __shared__ float red2[8][TPB];                  // 2KB
  __shared__ float scrR[8][4];
  __shared__ int lastFlag;

  const int tid = threadIdx.x;
  const int w = tid >> 6;
  const int l = tid & 63;
  const int tokbase = blockIdx.x * TPB;
  const float C0 = wsc[WS_C0];

  // zero axl tails (bytes 16..63 of each 64B row)
  if (tid < 192) {
    const int row = tid & 63;
    const int c = tid >> 6;
    const uint4 z = {0u, 0u, 0u, 0u};
    *(uint4*)((char*)axl + row * 64 + 16 + c * 16) = z;
  }

  // ---- phase 1: stream + in-register stats + fp8 X staging ----
  const int trow = tid >> 3;
  const int l8 = tid & 7;
  const int swz = (trow & 7) << 4;
  const size_t gbase = (size_t)(tokbase + trow) * 256 + l8 * 8;
  const float* ditg = wsc + WS_DIT + l8 * 8;
  const float* eg = wsc + WS_E + l8 * 8;
  float Ss = 0.f, Sm = 0.f, Sl = 0.f, Sc = 0.f;
#pragma unroll
  for (int t = 0; t < 4; ++t) {
    const float4 m0 = *(const float4*)(mu + gbase + t * 64);
    const float4 m1 = *(const float4*)(mu + gbase + t * 64 + 4);
    const float4 v0 = *(const float4*)(logvar + gbase + t * 64);
    const float4 v1 = *(const float4*)(logvar + gbase + t * 64 + 4);
    const float4 dA = *(const float4*)(ditg + t * 64);
    const float4 dB = *(const float4*)(ditg + t * 64 + 4);
    const float4 eA = *(const float4*)(eg + t * 64);
    const float4 eB = *(const float4*)(eg + t * 64 + 4);
#define CHUNK(m, lv, dt, ee)                                              \
  {                                                                       \
    const float va = __expf(lv.x), vb = __expf(lv.y), vc = __expf(lv.z),  \
                vd = __expf(lv.w);                                        \
    const float na = __expf(-lv.x), nb = __expf(-lv.y),                   \
                nc = __expf(-lv.z), nd = __expf(-lv.w);                   \
    const float qa = m.x * m.x, qb = m.y * m.y, qc = m.z * m.z,           \
                qd = m.w * m.w;                                           \
    Ss += (va + qa) * dt.x - m.x * ee.x + (vb + qb) * dt.y - m.y * ee.y + \
          (vc + qc) * dt.z - m.z * ee.z + (vd + qd) * dt.w - m.w * ee.w;  \
    Sm += qa + qb + qc + qd;                                              \
    Sl += lv.x + lv.y + lv.z + lv.w;                                      \
    Sc += qa * na + qb * nb + qc * nc + qd * nd;                          \
  }
    CHUNK(m0, v0, dA, eA);
    CHUNK(m1, v1, dB, eB);
#undef CHUNK
    uint4 u;
    u.x = pk4f8(m0.x, m0.y, m0.z, m0.w);
    u.y = pk4f8(m1.x, m1.y, m1.z, m1.w);
    u.z = pk4f8(v0.x, v0.y, v0.z, v0.w);
    u.w = pk4f8(v1.x, v1.y, v1.z, v1.w);
    const int col = trow * 512 + (t * 8 + l8) * 16;
    *(uint4*)(A_l + (col ^ swz)) = u;
  }
  Ss = row8_sum(Ss);
  Sm = row8_sum(Sm);
  Sl = row8_sum(Sl);
  Sc = row8_sum(Sc);
  if (l8 == 0) {
    const float sval = -0.5f * Ss + C0;
    const float mn = minutes[tokbase + trow];
    uint4 ex;
    ex.x = pk2(sval, mn);
    ex.y = pk2(sqrtf(Sm) * (1.0f / 16.0f), Sl * (1.0f / 256.0f));
    ex.z = pk2(Sc * (1.0f / 256.0f), 1.0f);
    ex.w = 0u;
    *(uint4*)((char*)axl + trow * 64) = ex;
    out_s[tokbase + trow] = sval;
    ws_score[tokbase + trow] = Sc;
  }
  __syncthreads();

  // ---- phase 2: 16 fp8 K-steps + 1 bf16 extras step; M=64, N=16 ----
  f32x4 a0 = {0.f, 0.f, 0.f, 0.f};
  f32x4 a1 = {0.f, 0.f, 0.f, 0.f};
  f32x4 a2 = {0.f, 0.f, 0.f, 0.f};
  f32x4 a3 = {0.f, 0.f, 0.f, 0.f};
  const int m_lane = l & 15;
  const int swzA = (m_lane & 7) << 4;
  const int rowA0 = m_lane * 512;
  const char* w1f = (const char*)(wsc + WS_W1F);
  const char* bp = w1f + w * 8192 + l * 8;
#pragma unroll 4
  for (int ks = 0; ks < 16; ++ks) {
    const int kOff = ks * 32 + (l >> 4) * 8;
    i64 bq = *(const i64*)(bp + ks * 512);
    i64 f0 = *(const i64*)(A_l + ((rowA0 + kOff) ^ swzA));
    i64 f1 = *(const i64*)(A_l + ((rowA0 + 16 * 512 + kOff) ^ swzA));
    i64 f2 = *(const i64*)(A_l + ((rowA0 + 32 * 512 + kOff) ^ swzA));
    i64 f3 = *(const i64*)(A_l + ((rowA0 + 48 * 512 + kOff) ^ swzA));
    a0 = __builtin_amdgcn_mfma_f32_16x16x32_fp8_fp8(f0, bq, a0, 0, 0, 0);
    a1 = __builtin_amdgcn_mfma_f32_16x16x32_fp8_fp8(f1, bq, a1, 0, 0, 0);
    a2 = __builtin_amdgcn_mfma_f32_16x16x32_fp8_fp8(f2, bq, a2, 0, 0, 0);
    a3 = __builtin_amdgcn_mfma_f32_16x16x32_fp8_fp8(f3, bq, a3, 0, 0, 0);
  }
  {  // bf16 extras + bias step (K-step 16)
    const int xb = (l >> 4) * 16;
    const ushort* w1x = (const ushort*)(wsc + WS_W1X);
    bf16x8 bq = *(const bf16x8*)(w1x + w * 512 + l * 8);
    bf16x8 f0 = *(const bf16x8*)((char*)axl + m_lane * 64 + xb);
    bf16x8 f1 = *(const bf16x8*)((char*)axl + (m_lane + 16) * 64 + xb);
    bf16x8 f2 = *(const bf16x8*)((char*)axl + (m_lane + 32) * 64 + xb);
    bf16x8 f3 = *(const bf16x8*)((char*)axl + (m_lane + 48) * 64 + xb);
    a0 = __builtin_amdgcn_mfma_f32_16x16x32_bf16(f0, bq, a0, 0, 0, 0);
    a1 = __builtin_amdgcn_mfma_f32_16x16x32_bf16(f1, bq, a1, 0, 0, 0);
    a2 = __builtin_amdgcn_mfma_f32_16x16x32_bf16(f2, bq, a2, 0, 0, 0);
    a3 = __builtin_amdgcn_mfma_f32_16x16x32_bf16(f3, bq, a3, 0, 0, 0);
  }

  // ---- epilogue: relu + W2 dot; DPP reduce over 16 h-lanes ----
  const int g = l >> 4;
  const float w2a = W2g[16 * w + m_lane];
#pragma unroll
  for (int mf = 0; mf < 4; ++mf) {
    const f32x4 aN = (mf == 0) ? a0 : (mf == 1) ? a1 : (mf == 2) ? a2 : a3;
#pragma unroll
    for (int r = 0; r < 4; ++r) {
      const int t_loc = 16 * mf + 4 * g + r;
      float cs = fmaxf(aN[r], 0.f) * w2a;
      cs = row16_sum(cs);
      if (m_lane == 0) red2[w][t_loc] = cs;
    }
  }
  __syncthreads();
  if (tid < TPB) {
    float z = red2[0][tid] + red2[1][tid] + red2[2][tid] + red2[3][tid] +
              red2[4][tid] + red2[5][tid] + red2[6][tid] + red2[7][tid] +
              b2[0];
    a_io[tokbase + tid] = 1.0f / (1.0f + __expf(-z));
  }
  __syncthreads();  // wave 0's a_io writes drained (vmcnt(0) before barrier)

  // ---- row completion signal (release) ----
  const int row = tokbase >> 9;  // 8 blocks per row of 512 tokens
  if (tid == 0) {
    __threadfence();  // flush this block's outputs to device scope
    const int old = atomicAdd(cnt + row, 1);
    lastFlag = (old == 7);
  }
  __syncthreads();
  if (!lastFlag) return;

  // ---- LAST block of the row: row reduction (512 threads, 1 token each) ----
  __threadfence();  // acquire: invalidate stale cached copies
  const int base = row << 9;
  const float sc = ws_score[base + tid];
  const float sv = out_s[base + tid];
  const float ar = a_io[base + tid];
  const float mn = minutes[base + tid];

  float vsc = wave_max(sc);
  float vmn = wave_max(mn);
  float var_ = wave_sum(ar);
  if (l == 0) {
    scrR[w][0] = vsc;
    scrR[w][1] = vmn;
    scrR[w][2] = var_;
  }
  __syncthreads();
  float msc = scrR[0][0], mmn = scrR[0][1], sar = scrR[0][2];
#pragma unroll
  for (int i = 1; i < 8; ++i) {
    msc = fmaxf(msc, scrR[i][0]);
    mmn = fmaxf(mmn, scrR[i][1]);
    sar += scrR[i][2];
  }
  const float e0 = __expf(sc - msc);
  float vse = wave_sum(e0);
  if (l == 0) scrR[w][3] = vse;
  __syncthreads();
  float se = 0.f;
#pragma unroll
  for (int i = 0; i < 8; ++i) se += scrR[i][3];

  const float lam = 1.0f / (1.0f + __expf(-attn_lambda_logit[0]));
  const float alpha = 1.0f / (1.0f + __expf(-alpha_logits[0]));
  const float rate = log1pf(__expf(decay_rate_log[0]));

  const float a00 = lam * ar / fmaxf(sar, 1e-6f) + (1.0f - lam) * e0 / se;
  const float dh = fmaxf(mmn - mn, 0.0f) * (1.0f / 60.0f);
  const float w0 = a00 * __expf(-rate * dh);
  float vsw = wave_sum(w0);
  if (l == 0) scrR[w][0] = vsw;  // reads of col0 all happened before B2
  __syncthreads();
  float sw = 0.f;
#pragma unroll
  for (int i = 0; i < 8; ++i) sw += scrR[i][0];
  const float af = w0 / fmaxf(sw, 1e-6f);
  a_io[base + tid] = af;

  const float sg = 1.0f / (1.0f + __expf(-sv));
  const float p = fminf(fmaxf(sg * af, 1e-6f), 1.0f - 1e-6f);
  float vsm = wave_sum(af * sv);
  float vlg = wave_sum(log1pf(-p));
  if (l == 0) {
    scrR[w][1] = vsm;
    scrR[w][2] = vlg;
  }
  __syncthreads();
  if (tid == 0) {
    float smain = 0.f, slg = 0.f;
#pragma unroll
    for (int i = 0; i < 8; ++i) {
      smain += scrR[i][1];
      slg += scrR[i][2];
    }
    float por = 1.0f - __expf(slg);
    por = fminf(fmaxf(por, 1e-6f), 1.0f - 1e-6f);
    const float sor = logf(por) - log1pf(-por);
    out_total[row] = alpha * smain + (1.0f - alpha) * sor;
  }
}

extern "C" void kernel_launch(void* const* d_in, const int* in_sizes, int n_in,
                              void* d_out, int out_size, void* d_ws,
                              size_t ws_size, hipStream_t stream) {
  const float* mu = (const float*)d_in[0];
  const float* logvar = (const float*)d_in[1];
  const float* minutes = (const float*)d_in[2];
  const float* mu_c = (const float*)d_in[3];
  const float* log_tau2 = (const float*)d_in[4];
  const float* log_prior = (const float*)d_in[5];
  const float* W1 = (const float*)d_in[6];
  const float* b1 = (const float*)d_in[7];
  const float* W2 = (const float*)d_in[8];
  const float* b2 = (const float*)d_in[9];
  const float* alpha_logits = (const float*)d_in[10];
  const float* attn_lambda_logit = (const float*)d_in[11];
  const float* decay_rate_log = (const float*)d_in[12];

  float* out = (float*)d_out;
  float* out_total = out;             // [256]
  float* out_s = out + B_DIM;        // [131072]
  float* out_a = out + B_DIM + NTOK; // [131072] araw then final a
  float* wsc = (float*)d_ws;
  float* ws_score = wsc + WS_SCORE;
  int* cnt = (int*)(wsc + WS_CNT);

  k_setup<<<128, 256, 0, stream>>>(W1, b1, mu_c, log_tau2, log_prior, wsc);
  k_fused<<<NTOK / TPB, 512, 0, stream>>>(
      mu, logvar, minutes, W2, b2, wsc, alpha_logits, attn_lambda_logit,
      decay_rate_log, out_total, out_s, ws_score, out_a, cnt);
}

// Round 13
// 56.488 us; speedup vs baseline: 8.7429x; 8.7429x over previous
//
#include <hip/hip_runtime.h>
#include <hip/hip_bf16.h>

#define B_DIM 256
#define NTOK (256 * 512)
#define W1_LD 517
#define TPB 64  // tokens per k_token block

// workspace float offsets
#define WS_DIT 0
#define WS_E 256             // holds 2*e
#define WS_C0 512
#define WS_W1F 1024          // fp8 frag-ordered [8 nblk][16 ks][64 lane][8B]
                             // = 65536 B = 16384 floats -> [1024, 17408)
#define WS_W1X 17408         // bf16 extras step [8 nblk][64 lane][8]
#define WS_SCORE 20480       // [NTOK]

typedef __attribute__((ext_vector_type(8))) short bf16x8;
typedef __attribute__((ext_vector_type(4))) float f32x4;
typedef long long i64;

__device__ __forceinline__ unsigned pk2(float a, float b) {
  __hip_bfloat162 h = __float22bfloat162_rn(make_float2(a, b));
  unsigned r;
  __builtin_memcpy(&r, &h, 4);
  return r;
}
// pack 4 floats -> 4 fp8 e4m3 bytes in one u32
__device__ __forceinline__ unsigned pk4f8(float a, float b, float c, float d) {
  int r = __builtin_amdgcn_cvt_pk_fp8_f32(a, b, 0, false);
  r = __builtin_amdgcn_cvt_pk_fp8_f32(c, d, r, true);
  return (unsigned)r;
}

// DPP cross-lane add (VALU pipe)
template <int CTRL>
__device__ __forceinline__ float dpp_add(float v) {
  int s = __builtin_amdgcn_update_dpp(0, __float_as_int(v), CTRL, 0xf, 0xf,
                                      true);
  return v + __int_as_float(s);
}
// sum over each group of 8 consecutive lanes (valid at lanes with (l&7)==0).
__device__ __forceinline__ float row8_sum(float v) {
  v = dpp_add<0xB1>(v);   // quad_perm xor1
  v = dpp_add<0x4E>(v);   // quad_perm xor2
  v = dpp_add<0x141>(v);  // row_half_mirror
  return v;
}
// sum over each group of 16 consecutive lanes
__device__ __forceinline__ float row16_sum(float v) {
  v = dpp_add<0xB1>(v);
  v = dpp_add<0x4E>(v);
  v = dpp_add<0x124>(v);  // row_ror:4
  v = dpp_add<0x128>(v);  // row_ror:8
  return v;
}

__device__ __forceinline__ float wave_sum(float v) {
#pragma unroll
  for (int off = 32; off > 0; off >>= 1) v += __shfl_xor(v, off, 64);
  return v;
}
__device__ __forceinline__ float wave_max(float v) {
#pragma unroll
  for (int off = 32; off > 0; off >>= 1) v = fmaxf(v, __shfl_xor(v, off, 64));
  return v;
}
__device__ __forceinline__ float block_sum(float v, float* scr) {
  v = wave_sum(v);
  int wid = threadIdx.x >> 6;
  __syncthreads();
  if ((threadIdx.x & 63) == 0) scr[wid] = v;
  __syncthreads();
  return scr[0] + scr[1] + scr[2] + scr[3];
}

// ---------------------------------------------------------------------------
// K-axis reorder: position p in [0,512) maps to source W1 column
//   (p&15)<8 ? (p>>4)*8 + (p&7) : 256 + (p>>4)*8 + (p&7)
// ---------------------------------------------------------------------------
__global__ __launch_bounds__(256) void k_setup(
    const float* __restrict__ W1, const float* __restrict__ b1,
    const float* __restrict__ mu_c, const float* __restrict__ log_tau2,
    const float* __restrict__ log_prior, float* __restrict__ wsc) {
  const int tid = threadIdx.x;
  const int h = blockIdx.x;
  const float* wr = W1 + h * W1_LD;
  {
    const int p = 2 * tid;
    const int c0 = ((p & 15) < 8) ? (p >> 4) * 8 + (p & 7)
                                  : 256 + (p >> 4) * 8 + (p & 7);
    const int p1 = p + 1;
    const int c1 = ((p1 & 15) < 8) ? (p1 >> 4) * 8 + (p1 & 7)
                                   : 256 + (p1 >> 4) * 8 + (p1 & 7);
    const int pk = __builtin_amdgcn_cvt_pk_fp8_f32(wr[c0], wr[c1], 0, false);
    char* w1f = (char*)(wsc + WS_W1F);
    const int off = (h >> 4) * 8192 + (p >> 5) * 512 +
                    (((p >> 3) & 3) * 16 + (h & 15)) * 8 + (p & 7);
    *(ushort*)(w1f + off) = (ushort)pk;
  }
  if (tid == 0) {
    ushort* w1x = (ushort*)(wsc + WS_W1X);
    const int nb = (h >> 4) * 512;
    uint4 g0;
    g0.x = pk2(wr[512], wr[513]);
    g0.y = pk2(wr[514], wr[515]);
    g0.z = pk2(wr[516], b1[h]);
    g0.w = 0u;
    *(uint4*)(w1x + nb + (h & 15) * 8) = g0;
    const uint4 z = {0u, 0u, 0u, 0u};
    *(uint4*)(w1x + nb + (16 + (h & 15)) * 8) = z;
    *(uint4*)(w1x + nb + (32 + (h & 15)) * 8) = z;
    *(uint4*)(w1x + nb + (48 + (h & 15)) * 8) = z;
  }

  if (blockIdx.x == 0) {
    __shared__ float scr[4];
    float lt0 = log_tau2[tid], lt1 = log_tau2[256 + tid];
    float mc0 = mu_c[tid], mc1 = mu_c[256 + tid];
    float it0 = __expf(-lt0), it1 = __expf(-lt1);
    wsc[WS_DIT + tid] = it1 - it0;
    wsc[WS_E + tid] = 2.0f * (mc1 * it1 - mc0 * it0);
    float g = mc1 * mc1 * it1 - mc0 * mc0 * it0 + (lt1 - lt0);
    float sg = block_sum(g, scr);
    if (tid == 0) wsc[WS_C0] = (log_prior[1] - log_prior[0]) - 0.5f * sg;
  }
}

// ---------------------------------------------------------------------------
// Token kernel: 64 tokens/block, 512 threads (8 waves), 4 blocks/CU
// (LDS 38.9 KB, 32 waves/CU). Wave w owns h in [16w, 16w+16) — B-fragment
// L2 traffic halved vs the 32-token tile (each B-frag serves 64 tokens).
// Phase 1: 8 lanes/token; stats in regs (DPP row8); fp8 X staged to
//          XOR-swizzled LDS (one uint4 write/iter). Extras row bf16 to axl.
// Phase 2: 16 fp8 K-steps + 1 bf16 extras step; M=64 (4 frags), N=16.
// ---------------------------------------------------------------------------
__global__ __launch_bounds__(512, 8) void k_token(
    const float* __restrict__ mu, const float* __restrict__ logvar,
    const float* __restrict__ minutes, const float* __restrict__ W2g,
    const float* __restrict__ b2, const float* __restrict__ wsc,
    float* __restrict__ out_s, float* __restrict__ ws_score,
    float* __restrict__ araw_out) {
  __shared__ __align__(16) char A_l[TPB * 512];   // 32KB fp8, XOR-swizzled
  __shared__ __align__(16) ushort axl[TPB * 32];  // 4KB bf16 extras rows
  __shared__ float red2[8][TPB];                  // 2KB

  const int tid = threadIdx.x;
  const int w = tid >> 6;
  const int l = tid & 63;
  const int tokbase = blockIdx.x * TPB;
  const float C0 = wsc[WS_C0];

  // zero axl tails (bytes 16..63 of each 64B row)
  if (tid < 192) {
    const int row = tid & 63;
    const int c = tid >> 6;
    const uint4 z = {0u, 0u, 0u, 0u};
    *(uint4*)((char*)axl + row * 64 + 16 + c * 16) = z;
  }

  // ---- phase 1: stream + in-register stats + fp8 X staging ----
  const int trow = tid >> 3;  // this thread's token, 0..63
  const int l8 = tid & 7;     // 8 lanes per token, 8 d per iter
  const int swz = (trow & 7) << 4;
  const size_t gbase = (size_t)(tokbase + trow) * 256 + l8 * 8;
  const float* ditg = wsc + WS_DIT + l8 * 8;
  const float* eg = wsc + WS_E + l8 * 8;
  float Ss = 0.f, Sm = 0.f, Sl = 0.f, Sc = 0.f;
#pragma unroll
  for (int t = 0; t < 4; ++t) {
    const float4 m0 = *(const float4*)(mu + gbase + t * 64);
    const float4 m1 = *(const float4*)(mu + gbase + t * 64 + 4);
    const float4 v0 = *(const float4*)(logvar + gbase + t * 64);
    const float4 v1 = *(const float4*)(logvar + gbase + t * 64 + 4);
    const float4 dA = *(const float4*)(ditg + t * 64);
    const float4 dB = *(const float4*)(ditg + t * 64 + 4);
    const float4 eA = *(const float4*)(eg + t * 64);
    const float4 eB = *(const float4*)(eg + t * 64 + 4);
#define CHUNK(m, lv, dt, ee)                                              \
  {                                                                       \
    const float va = __expf(lv.x), vb = __expf(lv.y), vc = __expf(lv.z),  \
                vd = __expf(lv.w);                                        \
    const float na = __expf(-lv.x), nb = __expf(-lv.y),                   \
                nc = __expf(-lv.z), nd = __expf(-lv.w);                   \
    const float qa = m.x * m.x, qb = m.y * m.y, qc = m.z * m.z,           \
                qd = m.w * m.w;                                           \
    Ss += (va + qa) * dt.x - m.x * ee.x + (vb + qb) * dt.y - m.y * ee.y + \
          (vc + qc) * dt.z - m.z * ee.z + (vd + qd) * dt.w - m.w * ee.w;  \
    Sm += qa + qb + qc + qd;                                              \
    Sl += lv.x + lv.y + lv.z + lv.w;                                      \
    Sc += qa * na + qb * nb + qc * nc + qd * nd;                          \
  }
    CHUNK(m0, v0, dA, eA);
    CHUNK(m1, v1, dB, eB);
#undef CHUNK
    uint4 u;
    u.x = pk4f8(m0.x, m0.y, m0.z, m0.w);
    u.y = pk4f8(m1.x, m1.y, m1.z, m1.w);
    u.z = pk4f8(v0.x, v0.y, v0.z, v0.w);
    u.w = pk4f8(v1.x, v1.y, v1.z, v1.w);
    const int col = trow * 512 + (t * 8 + l8) * 16;
    *(uint4*)(A_l + (col ^ swz)) = u;
  }
  Ss = row8_sum(Ss);
  Sm = row8_sum(Sm);
  Sl = row8_sum(Sl);
  Sc = row8_sum(Sc);
  if (l8 == 0) {
    const float sval = -0.5f * Ss + C0;
    const float mn = minutes[tokbase + trow];
    uint4 ex;
    ex.x = pk2(sval, mn);
    ex.y = pk2(sqrtf(Sm) * (1.0f / 16.0f), Sl * (1.0f / 256.0f));
    ex.z = pk2(Sc * (1.0f / 256.0f), 1.0f);
    ex.w = 0u;
    *(uint4*)((char*)axl + trow * 64) = ex;
    out_s[tokbase + trow] = sval;
    ws_score[tokbase + trow] = Sc;
  }
  __syncthreads();

  // ---- phase 2: 16 fp8 K-steps + 1 bf16 extras step; M=64, N=16 ----
  f32x4 a0 = {0.f, 0.f, 0.f, 0.f};
  f32x4 a1 = {0.f, 0.f, 0.f, 0.f};
  f32x4 a2 = {0.f, 0.f, 0.f, 0.f};
  f32x4 a3 = {0.f, 0.f, 0.f, 0.f};
  const int m_lane = l & 15;
  const int swzA = (m_lane & 7) << 4;
  const int rowA0 = m_lane * 512;
  const char* w1f = (const char*)(wsc + WS_W1F);
  const char* bp = w1f + w * 8192 + l * 8;
#pragma unroll 4
  for (int ks = 0; ks < 16; ++ks) {
    const int kOff = ks * 32 + (l >> 4) * 8;
    i64 bq = *(const i64*)(bp + ks * 512);
    i64 f0 = *(const i64*)(A_l + ((rowA0 + kOff) ^ swzA));
    i64 f1 = *(const i64*)(A_l + ((rowA0 + 16 * 512 + kOff) ^ swzA));
    i64 f2 = *(const i64*)(A_l + ((rowA0 + 32 * 512 + kOff) ^ swzA));
    i64 f3 = *(const i64*)(A_l + ((rowA0 + 48 * 512 + kOff) ^ swzA));
    a0 = __builtin_amdgcn_mfma_f32_16x16x32_fp8_fp8(f0, bq, a0, 0, 0, 0);
    a1 = __builtin_amdgcn_mfma_f32_16x16x32_fp8_fp8(f1, bq, a1, 0, 0, 0);
    a2 = __builtin_amdgcn_mfma_f32_16x16x32_fp8_fp8(f2, bq, a2, 0, 0, 0);
    a3 = __builtin_amdgcn_mfma_f32_16x16x32_fp8_fp8(f3, bq, a3, 0, 0, 0);
  }
  {  // bf16 extras + bias step (K-step 16)
    const int xb = (l >> 4) * 16;
    const ushort* w1x = (const ushort*)(wsc + WS_W1X);
    bf16x8 bq = *(const bf16x8*)(w1x + w * 512 + l * 8);
    bf16x8 f0 = *(const bf16x8*)((char*)axl + m_lane * 64 + xb);
    bf16x8 f1 = *(const bf16x8*)((char*)axl + (m_lane + 16) * 64 + xb);
    bf16x8 f2 = *(const bf16x8*)((char*)axl + (m_lane + 32) * 64 + xb);
    bf16x8 f3 = *(const bf16x8*)((char*)axl + (m_lane + 48) * 64 + xb);
    a0 = __builtin_amdgcn_mfma_f32_16x16x32_bf16(f0, bq, a0, 0, 0, 0);
    a1 = __builtin_amdgcn_mfma_f32_16x16x32_bf16(f1, bq, a1, 0, 0, 0);
    a2 = __builtin_amdgcn_mfma_f32_16x16x32_bf16(f2, bq, a2, 0, 0, 0);
    a3 = __builtin_amdgcn_mfma_f32_16x16x32_bf16(f3, bq, a3, 0, 0, 0);
  }

  // ---- epilogue: relu + W2 dot; DPP reduce over 16 h-lanes ----
  const int g = l >> 4;
  const float w2a = W2g[16 * w + m_lane];
#pragma unroll
  for (int mf = 0; mf < 4; ++mf) {
    const f32x4 aN = (mf == 0) ? a0 : (mf == 1) ? a1 : (mf == 2) ? a2 : a3;
#pragma unroll
    for (int r = 0; r < 4; ++r) {
      const int t_loc = 16 * mf + 4 * g + r;
      float cs = fmaxf(aN[r], 0.f) * w2a;
      cs = row16_sum(cs);
      if (m_lane == 0) red2[w][t_loc] = cs;
    }
  }
  __syncthreads();
  if (tid < TPB) {
    float z = red2[0][tid] + red2[1][tid] + red2[2][tid] + red2[3][tid] +
              red2[4][tid] + red2[5][tid] + red2[6][tid] + red2[7][tid] +
              b2[0];
    araw_out[tokbase + tid] = 1.0f / (1.0f + __expf(-z));
  }
}

// ---------------------------------------------------------------------------
// Per-batch-row kernel: 256 blocks, 256 threads x 2 tokens; 4 barriers.
// ---------------------------------------------------------------------------
__global__ __launch_bounds__(256) void k_row(
    const float* __restrict__ minutes, const float* __restrict__ s_in,
    const float* __restrict__ score_in, float* a_io,
    const float* __restrict__ alpha_logits,
    const float* __restrict__ attn_lambda_logit,
    const float* __restrict__ decay_rate_log, float* __restrict__ out_total) {
  __shared__ float scrA[4][4];
  __shared__ float scrB[4];
  __shared__ float scrC[4];
  __shared__ float scrD[4][2];
  const int row = blockIdx.x;
  const int tid = threadIdx.x;
  const int w = tid >> 6;
  const int base = row * 512;
  const float sc0 = score_in[base + tid], sc1 = score_in[base + 256 + tid];
  const float sv0 = s_in[base + tid], sv1 = s_in[base + 256 + tid];
  const float ar0 = a_io[base + tid], ar1 = a_io[base + 256 + tid];
  const float mn0 = minutes[base + tid], mn1 = minutes[base + 256 + tid];

  const float vsc = wave_max(fmaxf(sc0, sc1));
  const float vmn = wave_max(fmaxf(mn0, mn1));
  const float var_ = wave_sum(ar0 + ar1);
  if ((tid & 63) == 0) {
    scrA[w][0] = vsc;
    scrA[w][1] = vmn;
    scrA[w][2] = var_;
  }
  __syncthreads();
  const float msc = fmaxf(fmaxf(scrA[0][0], scrA[1][0]),
                          fmaxf(scrA[2][0], scrA[3][0]));
  const float mmn = fmaxf(fmaxf(scrA[0][1], scrA[1][1]),
                          fmaxf(scrA[2][1], scrA[3][1]));
  const float sar = scrA[0][2] + scrA[1][2] + scrA[2][2] + scrA[3][2];

  const float e0 = __expf(sc0 - msc), e1 = __expf(sc1 - msc);
  const float vse = wave_sum(e0 + e1);
  if ((tid & 63) == 0) scrB[w] = vse;
  __syncthreads();
  const float se = scrB[0] + scrB[1] + scrB[2] + scrB[3];

  const float lam = 1.0f / (1.0f + __expf(-attn_lambda_logit[0]));
  const float alpha = 1.0f / (1.0f + __expf(-alpha_logits[0]));
  const float rate = log1pf(__expf(decay_rate_log[0]));

  const float inv_sar = 1.0f / fmaxf(sar, 1e-6f);
  const float inv_se = 1.0f / se;
  const float a00 = lam * ar0 * inv_sar + (1.0f - lam) * e0 * inv_se;
  const float a01 = lam * ar1 * inv_sar + (1.0f - lam) * e1 * inv_se;
  const float dh0 = fmaxf(mmn - mn0, 0.0f) * (1.0f / 60.0f);
  const float dh1 = fmaxf(mmn - mn1, 0.0f) * (1.0f / 60.0f);
  const float w0 = a00 * __expf(-rate * dh0);
  const float w1 = a01 * __expf(-rate * dh1);
  const float vsw = wave_sum(w0 + w1);
  if ((tid & 63) == 0) scrC[w] = vsw;
  __syncthreads();
  const float sw = scrC[0] + scrC[1] + scrC[2] + scrC[3];
  const float inv_sw = 1.0f / fmaxf(sw, 1e-6f);
  const float af0 = w0 * inv_sw, af1 = w1 * inv_sw;
  a_io[base + tid] = af0;
  a_io[base + 256 + tid] = af1;

  const float sg0 = 1.0f / (1.0f + __expf(-sv0));
  const float sg1 = 1.0f / (1.0f + __expf(-sv1));
  const float p0 = fminf(fmaxf(sg0 * af0, 1e-6f), 1.0f - 1e-6f);
  const float p1 = fminf(fmaxf(sg1 * af1, 1e-6f), 1.0f - 1e-6f);
  const float vsm = wave_sum(af0 * sv0 + af1 * sv1);
  const float vlg = wave_sum(log1pf(-p0) + log1pf(-p1));
  if ((tid & 63) == 0) {
    scrD[w][0] = vsm;
    scrD[w][1] = vlg;
  }
  __syncthreads();
  if (tid == 0) {
    const float smain = scrD[0][0] + scrD[1][0] + scrD[2][0] + scrD[3][0];
    const float slg = scrD[0][1] + scrD[1][1] + scrD[2][1] + scrD[3][1];
    float por = 1.0f - __expf(slg);
    por = fminf(fmaxf(por, 1e-6f), 1.0f - 1e-6f);
    const float sor = logf(por) - log1pf(-por);
    out_total[row] = alpha * smain + (1.0f - alpha) * sor;
  }
}

extern "C" void kernel_launch(void* const* d_in, const int* in_sizes, int n_in,
                              void* d_out, int out_size, void* d_ws,
                              size_t ws_size, hipStream_t stream) {
  const float* mu = (const float*)d_in[0];
  const float* logvar = (const float*)d_in[1];
  const float* minutes = (const float*)d_in[2];
  const float* mu_c = (const float*)d_in[3];
  const float* log_tau2 = (const float*)d_in[4];
  const float* log_prior = (const float*)d_in[5];
  const float* W1 = (const float*)d_in[6];
  const float* b1 = (const float*)d_in[7];
  const float* W2 = (const float*)d_in[8];
  const float* b2 = (const float*)d_in[9];
  const float* alpha_logits = (const float*)d_in[10];
  const float* attn_lambda_logit = (const float*)d_in[11];
  const float* decay_rate_log = (const float*)d_in[12];

  float* out = (float*)d_out;
  float* out_total = out;             // [256]
  float* out_s = out + B_DIM;        // [131072]
  float* out_a = out + B_DIM + NTOK; // [131072] — holds a_raw between kernels
  float* wsc = (float*)d_ws;
  float* ws_score = wsc + WS_SCORE;

  k_setup<<<128, 256, 0, stream>>>(W1, b1, mu_c, log_tau2, log_prior, wsc);
  k_token<<<NTOK / TPB, 512, 0, stream>>>(mu, logvar, minutes, W2, b2, wsc,
                                          out_s, ws_score, out_a);
  k_row<<<B_DIM, 256, 0, stream>>>(minutes, out_s, ws_score, out_a,
                                   alpha_logits, attn_lambda_logit,
                                   decay_rate_log, out_total);
}